// Round 12
// baseline (98.485 us; speedup 1.0000x reference)
//
#include <hip/hip_runtime.h>

#define BSZ 16
#define SSZ 8192
#define F4  64
#define EPSV 1e-5f
#define SEGCAP 256     // nseg ~131 expected (sigma ~11) -> huge margin
#define CHCAP  384     // max chunks = SSZ/CH (64) + SEGCAP
#define CH 128
#define NBLK_S 4096

typedef float f32x4 __attribute__((ext_vector_type(4)));

__device__ __forceinline__ int wave_scan_incl(int x) {
    const int lane = threadIdx.x & 63;
#pragma unroll
    for (int o = 1; o < 64; o <<= 1) {
        int v = __shfl_up(x, o, 64);
        if (lane >= o) x += v;
    }
    return x;
}

// inclusive scan over 1024 threads; 2 barriers
__device__ __forceinline__ int block_scan_incl(int x, int* lds16) {
    const int wid = threadIdx.x >> 6;
    const int lane = threadIdx.x & 63;
    int w = wave_scan_incl(x);
    if (lane == 63) lds16[wid] = w;
    __syncthreads();
    int base = 0;
#pragma unroll
    for (int j = 0; j < 16; ++j) base += (j < wid) ? lds16[j] : 0;
    __syncthreads();
    return base + w;
}

// --- Kernel 1: fused cp-reduce + scan -> chunk metadata + seg_id ---------
__global__ __launch_bounds__(1024) void scan_kernel(const int* __restrict__ cp,
                                                    int* __restrict__ ch_s0,
                                                    int* __restrict__ ch_s1,
                                                    int* __restrict__ ch_c0,
                                                    int* __restrict__ ch_n,
                                                    int* __restrict__ ch_seg,
                                                    float* __restrict__ ch_rc,
                                                    int* __restrict__ seg_id,
                                                    int* __restrict__ ctr,
                                                    int* __restrict__ meta) {
    __shared__ int lds16[16];
    __shared__ int sstart[SEGCAP];
    __shared__ int snseg;
    __shared__ int stot;
    const int t = threadIdx.x;
    for (int i = t; i < CHCAP * BSZ; i += 1024) ctr[i] = 0;  // replay-safe

    int vals[8];
    {
        const int4* cp4 = (const int4*)cp;
        int4 a0 = {0, 0, 0, 0}, a1 = {0, 0, 0, 0};
#pragma unroll
        for (int b = 0; b < BSZ; ++b) {
            int4 u = cp4[b * 2048 + t * 2];
            int4 v = cp4[b * 2048 + t * 2 + 1];
            a0.x |= u.x; a0.y |= u.y; a0.z |= u.z; a0.w |= u.w;
            a1.x |= v.x; a1.y |= v.y; a1.z |= v.z; a1.w |= v.w;
        }
        vals[0] = a0.x != 0; vals[1] = a0.y != 0; vals[2] = a0.z != 0; vals[3] = a0.w != 0;
        vals[4] = a1.x != 0; vals[5] = a1.y != 0; vals[6] = a1.z != 0; vals[7] = a1.w != 0;
        if (t == 0) vals[0] = 0;   // position 0 never splits
    }
    int tot = 0;
#pragma unroll
    for (int i = 0; i < 8; ++i) tot += vals[i];

    const int incl = block_scan_incl(tot, lds16);
    int run = incl - tot;
#pragma unroll
    for (int i = 0; i < 8; ++i) {
        run += vals[i];
        int r = run < SEGCAP ? run : SEGCAP - 1;
        if (vals[i] && run < SEGCAP) sstart[run] = t * 8 + i;
        seg_id[t * 8 + i] = r;
    }
    if (t == 0) sstart[0] = 0;
    if (t == 1023) { int n = incl + 1; snseg = n < SEGCAP ? n : SEGCAP; }
    __syncthreads();

    const int nseg = snseg;
    int st = 0, en = 0, nch = 0;
    if (t < nseg) {
        st = sstart[t];
        en = (t + 1 < nseg) ? sstart[t + 1] : SSZ;
        nch = (en - st + CH - 1) / CH;
    }
    const int incl2 = block_scan_incl(nch, lds16);
    const int cbase = incl2 - nch;
    if (t < nseg) {
        const float rc = 1.0f / (float)(en - st);
        for (int j = 0; j < nch; ++j) {
            const int c = cbase + j;
            ch_s0[c] = st + j * CH;
            ch_s1[c] = min(en, st + (j + 1) * CH);
            ch_c0[c] = cbase;
            ch_n[c]  = nch;
            ch_seg[c] = t;
            ch_rc[c] = rc;
        }
    }
    if (t == 1023) stot = incl2;
    __syncthreads();
    if (t == 0) meta[0] = stot * BSZ;
}

// --- Kernel 2: balanced stats + fence-free closer finalize ---------------
__global__ __launch_bounds__(256) void stats_kernel(const f32x4* __restrict__ x4,
                                                    const int* __restrict__ ch_s0,
                                                    const int* __restrict__ ch_s1,
                                                    const int* __restrict__ ch_c0,
                                                    const int* __restrict__ ch_n,
                                                    const int* __restrict__ ch_seg,
                                                    const float* __restrict__ ch_rc,
                                                    const int* __restrict__ meta,
                                                    float* __restrict__ psum,
                                                    float* __restrict__ pssq,
                                                    int* __restrict__ ctr,
                                                    f32x4* __restrict__ mean4,
                                                    f32x4* __restrict__ rstd4) {
    __shared__ f32x4 lsum[4][64];
    __shared__ f32x4 lssq[4][64];
    __shared__ int lcloser;
    const int nitems = meta[0];
    const int lane = threadIdx.x & 63;
    const int wave = threadIdx.x >> 6;
    for (int item = blockIdx.x; item < nitems; item += NBLK_S) {
        const int c = item >> 4;
        const int b = item & 15;
        const int s0 = ch_s0[c], s1 = ch_s1[c];
        const int n = ch_n[c];
        const int seg = ch_seg[c];
        const float rc = ch_rc[c];
        const f32x4* px = x4 + (size_t)b * SSZ * F4 + lane;

        f32x4 sum = {0.f, 0.f, 0.f, 0.f};
        f32x4 ssq = {0.f, 0.f, 0.f, 0.f};
        if (s1 - s0 == CH) {
            // full chunk: fixed trip count (CH/4 = 32 iters) -> unrolled ILP
            const int r0 = s0 + wave;
#pragma unroll 8
            for (int r = 0; r < CH / 4; ++r) {
                f32x4 v = px[(size_t)(r0 + 4 * r) * F4];
                sum += v;
                ssq += v * v;
            }
        } else {
            for (int s = s0 + wave; s < s1; s += 4) {
                f32x4 v = px[(size_t)s * F4];
                sum += v;
                ssq += v * v;
            }
        }
        lsum[wave][lane] = sum;
        lssq[wave][lane] = ssq;
        __syncthreads();

        if (n == 1) {
            if (wave == 0) {
                f32x4 S = lsum[0][lane] + lsum[1][lane] + lsum[2][lane] + lsum[3][lane];
                f32x4 Q = lssq[0][lane] + lssq[1][lane] + lssq[2][lane] + lssq[3][lane];
                f32x4 m = S * rc;
                f32x4 var = Q * rc - m * m;
                f32x4 r;
                r.x = 1.0f / sqrtf(fmaxf(var.x, 0.f) + EPSV);
                r.y = 1.0f / sqrtf(fmaxf(var.y, 0.f) + EPSV);
                r.z = 1.0f / sqrtf(fmaxf(var.z, 0.f) + EPSV);
                r.w = 1.0f / sqrtf(fmaxf(var.w, 0.f) + EPSV);
                mean4[((size_t)seg * BSZ + b) * F4 + lane] = m;
                rstd4[((size_t)seg * BSZ + b) * F4 + lane] = r;
            }
            __syncthreads();
        } else {
            const int c0 = ch_c0[c];
            const size_t pb = ((size_t)c * BSZ + b) * F4 * 4 + lane * 4;
            if (wave == 0) {
                f32x4 o = lsum[0][lane] + lsum[1][lane] + lsum[2][lane] + lsum[3][lane];
#pragma unroll
                for (int j = 0; j < 4; ++j)
                    __hip_atomic_store(&psum[pb + j], o[j], __ATOMIC_RELAXED,
                                       __HIP_MEMORY_SCOPE_AGENT);
            } else if (wave == 1) {
                f32x4 o = lssq[0][lane] + lssq[1][lane] + lssq[2][lane] + lssq[3][lane];
#pragma unroll
                for (int j = 0; j < 4; ++j)
                    __hip_atomic_store(&pssq[pb + j], o[j], __ATOMIC_RELAXED,
                                       __HIP_MEMORY_SCOPE_AGENT);
            }
            __syncthreads();   // vmcnt drained before barrier: stores visible
            if (threadIdx.x == 0) {
                int ret = __hip_atomic_fetch_add(&ctr[c0 * BSZ + b], 1,
                                                 __ATOMIC_RELAXED,
                                                 __HIP_MEMORY_SCOPE_AGENT);
                lcloser = (ret == n - 1);
            }
            __syncthreads();
            if (lcloser && wave == 0) {
                f32x4 S = {0.f, 0.f, 0.f, 0.f};
                f32x4 Q = {0.f, 0.f, 0.f, 0.f};
                for (int cc = c0; cc < c0 + n; ++cc) {
                    const size_t qb = ((size_t)cc * BSZ + b) * F4 * 4 + lane * 4;
#pragma unroll
                    for (int j = 0; j < 4; ++j) {
                        S[j] += __hip_atomic_load(&psum[qb + j], __ATOMIC_RELAXED,
                                                  __HIP_MEMORY_SCOPE_AGENT);
                        Q[j] += __hip_atomic_load(&pssq[qb + j], __ATOMIC_RELAXED,
                                                  __HIP_MEMORY_SCOPE_AGENT);
                    }
                }
                f32x4 m = S * rc;
                f32x4 var = Q * rc - m * m;
                f32x4 r;
                r.x = 1.0f / sqrtf(fmaxf(var.x, 0.f) + EPSV);
                r.y = 1.0f / sqrtf(fmaxf(var.y, 0.f) + EPSV);
                r.z = 1.0f / sqrtf(fmaxf(var.z, 0.f) + EPSV);
                r.w = 1.0f / sqrtf(fmaxf(var.w, 0.f) + EPSV);
                mean4[((size_t)seg * BSZ + b) * F4 + lane] = m;
                rstd4[((size_t)seg * BSZ + b) * F4 + lane] = r;
            }
            __syncthreads();
        }
    }
}

// --- Kernel 3: normalize, 2 b-slices per thread, plain stores ------------
__global__ __launch_bounds__(256) void norm_kernel(const f32x4* __restrict__ x4,
                                                   const f32x4* __restrict__ w4p,
                                                   const f32x4* __restrict__ b4p,
                                                   const int* __restrict__ seg_id,
                                                   const f32x4* __restrict__ mean4,
                                                   const f32x4* __restrict__ rstd4,
                                                   f32x4* __restrict__ out4) {
    const int tid = blockIdx.x * 256 + threadIdx.x;  // [0, BSZ/2*SSZ*F4)
    const int f4i = tid & 63;
    const int s = (tid >> 6) & (SSZ - 1);
    const int bh = tid >> 19;                        // [0, 8)
    const int seg = seg_id[s];
    const f32x4 w = w4p[f4i];
    const f32x4 bb = b4p[f4i];

    const size_t xi = (size_t)s * F4 + f4i;
    const int b0 = bh, b1 = bh + 8;
    const size_t mi = (size_t)seg * BSZ * F4 + f4i;

    const f32x4 v0 = x4[xi + (size_t)b0 * SSZ * F4];
    const f32x4 v1 = x4[xi + (size_t)b1 * SSZ * F4];
    const f32x4 m0 = mean4[mi + b0 * F4];
    const f32x4 m1 = mean4[mi + b1 * F4];
    const f32x4 r0 = rstd4[mi + b0 * F4];
    const f32x4 r1 = rstd4[mi + b1 * F4];
    out4[xi + (size_t)b0 * SSZ * F4] = (v0 - m0) * r0 * w + bb;
    out4[xi + (size_t)b1 * SSZ * F4] = (v1 - m1) * r1 * w + bb;
}

extern "C" void kernel_launch(void* const* d_in, const int* in_sizes, int n_in,
                              void* d_out, int out_size, void* d_ws, size_t ws_size,
                              hipStream_t stream) {
    const f32x4* x = (const f32x4*)d_in[0];
    const f32x4* w = (const f32x4*)d_in[1];
    const f32x4* bias = (const f32x4*)d_in[2];
    const int* cp = (const int*)d_in[3];

    char* ws = (char*)d_ws;
    int*   meta  = (int*)ws;                 // [16]
    int*   ch_s0 = (int*)(ws + 2048);        // [CHCAP]
    int*   ch_s1 = (int*)(ws + 4096);        // [CHCAP]
    int*   ch_c0 = (int*)(ws + 6144);        // [CHCAP]
    int*   ch_n  = (int*)(ws + 8192);        // [CHCAP]
    int*   ch_seg= (int*)(ws + 10240);       // [CHCAP]
    float* ch_rc = (float*)(ws + 12288);     // [CHCAP]
    int*   ctr   = (int*)(ws + 32768);       // [CHCAP*BSZ] = 24 KB
    int*   seg_id= (int*)(ws + 65536);       // [SSZ]
    float* psum  = (float*)(ws + 131072);    // CHCAP*BSZ*FSZ = 6.29 MB
    float* pssq  = psum + (size_t)CHCAP * BSZ * F4 * 4;
    f32x4* mean4 = (f32x4*)(pssq + (size_t)CHCAP * BSZ * F4 * 4);  // 4.2 MB
    f32x4* rstd4 = mean4 + (size_t)SEGCAP * BSZ * F4;

    scan_kernel<<<1, 1024, 0, stream>>>(cp, ch_s0, ch_s1, ch_c0, ch_n, ch_seg,
                                        ch_rc, seg_id, ctr, meta);
    stats_kernel<<<NBLK_S, 256, 0, stream>>>(x, ch_s0, ch_s1, ch_c0, ch_n, ch_seg,
                                             ch_rc, meta, psum, pssq, ctr,
                                             mean4, rstd4);
    norm_kernel<<<BSZ * SSZ * F4 / 2 / 256, 256, 0, stream>>>(x, w, bias, seg_id,
                                                              mean4, rstd4,
                                                              (f32x4*)d_out);
}

// Round 13
// 91.869 us; speedup vs baseline: 1.0720x; 1.0720x over previous
//
#include <hip/hip_runtime.h>

#define BSZ 16
#define SSZ 8192
#define F4  64
#define EPSV 1e-5f
#define SEGCAP 256     // nseg ~131 expected (sigma ~11) -> huge margin
#define CHCAP  384     // max chunks = SSZ/CH (128) + SEGCAP
#define CH 64
#define NBLK_S 4096

typedef float f32x4 __attribute__((ext_vector_type(4)));

__device__ __forceinline__ int wave_scan_incl(int x) {
    const int lane = threadIdx.x & 63;
#pragma unroll
    for (int o = 1; o < 64; o <<= 1) {
        int v = __shfl_up(x, o, 64);
        if (lane >= o) x += v;
    }
    return x;
}

// inclusive scan over 1024 threads; 2 barriers
__device__ __forceinline__ int block_scan_incl(int x, int* lds16) {
    const int wid = threadIdx.x >> 6;
    const int lane = threadIdx.x & 63;
    int w = wave_scan_incl(x);
    if (lane == 63) lds16[wid] = w;
    __syncthreads();
    int base = 0;
#pragma unroll
    for (int j = 0; j < 16; ++j) base += (j < wid) ? lds16[j] : 0;
    __syncthreads();
    return base + w;
}

// --- Kernel 1: fused cp-reduce + scan -> chunk metadata + seg_id ---------
__global__ __launch_bounds__(1024) void scan_kernel(const int* __restrict__ cp,
                                                    int* __restrict__ ch_s0,
                                                    int* __restrict__ ch_s1,
                                                    int* __restrict__ ch_c0,
                                                    int* __restrict__ ch_n,
                                                    int* __restrict__ ch_seg,
                                                    float* __restrict__ ch_rc,
                                                    int* __restrict__ seg_id,
                                                    int* __restrict__ ctr,
                                                    int* __restrict__ meta) {
    __shared__ int lds16[16];
    __shared__ int sstart[SEGCAP];
    __shared__ int snseg;
    __shared__ int stot;
    const int t = threadIdx.x;
    for (int i = t; i < CHCAP * BSZ; i += 1024) ctr[i] = 0;  // replay-safe

    // fused cp_reduce: this thread owns s = t*8 .. t*8+7
    int vals[8];
    {
        const int4* cp4 = (const int4*)cp;
        int4 a0 = {0, 0, 0, 0}, a1 = {0, 0, 0, 0};
#pragma unroll
        for (int b = 0; b < BSZ; ++b) {
            int4 u = cp4[b * 2048 + t * 2];
            int4 v = cp4[b * 2048 + t * 2 + 1];
            a0.x |= u.x; a0.y |= u.y; a0.z |= u.z; a0.w |= u.w;
            a1.x |= v.x; a1.y |= v.y; a1.z |= v.z; a1.w |= v.w;
        }
        vals[0] = a0.x != 0; vals[1] = a0.y != 0; vals[2] = a0.z != 0; vals[3] = a0.w != 0;
        vals[4] = a1.x != 0; vals[5] = a1.y != 0; vals[6] = a1.z != 0; vals[7] = a1.w != 0;
        if (t == 0) vals[0] = 0;   // position 0 never splits
    }
    int tot = 0;
#pragma unroll
    for (int i = 0; i < 8; ++i) tot += vals[i];

    const int incl = block_scan_incl(tot, lds16);
    int run = incl - tot;  // exclusive prefix
#pragma unroll
    for (int i = 0; i < 8; ++i) {
        run += vals[i];
        int r = run < SEGCAP ? run : SEGCAP - 1;
        if (vals[i] && run < SEGCAP) sstart[run] = t * 8 + i;
        seg_id[t * 8 + i] = r;
    }
    if (t == 0) sstart[0] = 0;
    if (t == 1023) { int n = incl + 1; snseg = n < SEGCAP ? n : SEGCAP; }
    __syncthreads();

    const int nseg = snseg;
    int st = 0, en = 0, nch = 0;
    if (t < nseg) {
        st = sstart[t];
        en = (t + 1 < nseg) ? sstart[t + 1] : SSZ;
        nch = (en - st + CH - 1) / CH;
    }
    const int incl2 = block_scan_incl(nch, lds16);
    const int cbase = incl2 - nch;
    if (t < nseg) {
        const float rc = 1.0f / (float)(en - st);
        for (int j = 0; j < nch; ++j) {
            const int c = cbase + j;
            ch_s0[c] = st + j * CH;
            ch_s1[c] = min(en, st + (j + 1) * CH);
            ch_c0[c] = cbase;
            ch_n[c]  = nch;
            ch_seg[c] = t;
            ch_rc[c] = rc;
        }
    }
    if (t == 1023) stot = incl2;   // total chunks
    __syncthreads();
    if (t == 0) meta[0] = stot * BSZ;
}

// --- Kernel 2: balanced stats + FENCE-FREE closer finalize (R10 proven) --
__global__ __launch_bounds__(256) void stats_kernel(const f32x4* __restrict__ x4,
                                                    const int* __restrict__ ch_s0,
                                                    const int* __restrict__ ch_s1,
                                                    const int* __restrict__ ch_c0,
                                                    const int* __restrict__ ch_n,
                                                    const int* __restrict__ ch_seg,
                                                    const float* __restrict__ ch_rc,
                                                    const int* __restrict__ meta,
                                                    float* __restrict__ psum,
                                                    float* __restrict__ pssq,
                                                    int* __restrict__ ctr,
                                                    f32x4* __restrict__ mean4,
                                                    f32x4* __restrict__ rstd4) {
    __shared__ f32x4 lsum[4][64];
    __shared__ f32x4 lssq[4][64];
    __shared__ int lcloser;
    const int nitems = meta[0];
    const int lane = threadIdx.x & 63;
    const int wave = threadIdx.x >> 6;
    for (int item = blockIdx.x; item < nitems; item += NBLK_S) {
        const int c = item >> 4;
        const int b = item & 15;
        const int s0 = ch_s0[c], s1 = ch_s1[c];
        const int n = ch_n[c];
        const int seg = ch_seg[c];
        const float rc = ch_rc[c];
        const f32x4* px = x4 + (size_t)b * SSZ * F4 + lane;

        f32x4 sum = {0.f, 0.f, 0.f, 0.f};
        f32x4 ssq = {0.f, 0.f, 0.f, 0.f};
        for (int s = s0 + wave; s < s1; s += 4) {
            f32x4 v = px[(size_t)s * F4];
            sum += v;
            ssq += v * v;
        }
        lsum[wave][lane] = sum;
        lssq[wave][lane] = ssq;
        __syncthreads();

        if (n == 1) {
            if (wave == 0) {
                f32x4 S = lsum[0][lane] + lsum[1][lane] + lsum[2][lane] + lsum[3][lane];
                f32x4 Q = lssq[0][lane] + lssq[1][lane] + lssq[2][lane] + lssq[3][lane];
                f32x4 m = S * rc;
                f32x4 var = Q * rc - m * m;
                f32x4 r;
                r.x = 1.0f / sqrtf(fmaxf(var.x, 0.f) + EPSV);
                r.y = 1.0f / sqrtf(fmaxf(var.y, 0.f) + EPSV);
                r.z = 1.0f / sqrtf(fmaxf(var.z, 0.f) + EPSV);
                r.w = 1.0f / sqrtf(fmaxf(var.w, 0.f) + EPSV);
                mean4[((size_t)seg * BSZ + b) * F4 + lane] = m;
                rstd4[((size_t)seg * BSZ + b) * F4 + lane] = r;
            }
            __syncthreads();
        } else {
            const int c0 = ch_c0[c];
            const size_t pb = ((size_t)c * BSZ + b) * F4 * 4 + lane * 4;
            if (wave == 0) {
                f32x4 o = lsum[0][lane] + lsum[1][lane] + lsum[2][lane] + lsum[3][lane];
#pragma unroll
                for (int j = 0; j < 4; ++j)
                    __hip_atomic_store(&psum[pb + j], o[j], __ATOMIC_RELAXED,
                                       __HIP_MEMORY_SCOPE_AGENT);
            } else if (wave == 1) {
                f32x4 o = lssq[0][lane] + lssq[1][lane] + lssq[2][lane] + lssq[3][lane];
#pragma unroll
                for (int j = 0; j < 4; ++j)
                    __hip_atomic_store(&pssq[pb + j], o[j], __ATOMIC_RELAXED,
                                       __HIP_MEMORY_SCOPE_AGENT);
            }
            __syncthreads();   // vmcnt drained before barrier: stores visible
            if (threadIdx.x == 0) {
                int ret = __hip_atomic_fetch_add(&ctr[c0 * BSZ + b], 1,
                                                 __ATOMIC_RELAXED,
                                                 __HIP_MEMORY_SCOPE_AGENT);
                lcloser = (ret == n - 1);
            }
            __syncthreads();
            if (lcloser && wave == 0) {
                f32x4 S = {0.f, 0.f, 0.f, 0.f};
                f32x4 Q = {0.f, 0.f, 0.f, 0.f};
                for (int cc = c0; cc < c0 + n; ++cc) {
                    const size_t qb = ((size_t)cc * BSZ + b) * F4 * 4 + lane * 4;
#pragma unroll
                    for (int j = 0; j < 4; ++j) {
                        S[j] += __hip_atomic_load(&psum[qb + j], __ATOMIC_RELAXED,
                                                  __HIP_MEMORY_SCOPE_AGENT);
                        Q[j] += __hip_atomic_load(&pssq[qb + j], __ATOMIC_RELAXED,
                                                  __HIP_MEMORY_SCOPE_AGENT);
                    }
                }
                f32x4 m = S * rc;
                f32x4 var = Q * rc - m * m;
                f32x4 r;
                r.x = 1.0f / sqrtf(fmaxf(var.x, 0.f) + EPSV);
                r.y = 1.0f / sqrtf(fmaxf(var.y, 0.f) + EPSV);
                r.z = 1.0f / sqrtf(fmaxf(var.z, 0.f) + EPSV);
                r.w = 1.0f / sqrtf(fmaxf(var.w, 0.f) + EPSV);
                mean4[((size_t)seg * BSZ + b) * F4 + lane] = m;
                rstd4[((size_t)seg * BSZ + b) * F4 + lane] = r;
            }
            __syncthreads();
        }
    }
}

// --- Kernel 3: flat normalize, one f32x4 element per thread, NT stores ---
__global__ __launch_bounds__(256) void norm_kernel(const f32x4* __restrict__ x4,
                                                   const f32x4* __restrict__ w4p,
                                                   const f32x4* __restrict__ b4p,
                                                   const int* __restrict__ seg_id,
                                                   const f32x4* __restrict__ mean4,
                                                   const f32x4* __restrict__ rstd4,
                                                   f32x4* __restrict__ out4) {
    const int tid = blockIdx.x * 256 + threadIdx.x;  // [0, BSZ*SSZ*F4)
    const int f4i = tid & 63;
    const int s = (tid >> 6) & (SSZ - 1);
    const int b = tid >> 19;                         // / (SSZ*F4)
    const int seg = seg_id[s];
    const f32x4 m = mean4[((size_t)seg * BSZ + b) * F4 + f4i];
    const f32x4 r = rstd4[((size_t)seg * BSZ + b) * F4 + f4i];
    const f32x4 w = w4p[f4i];
    const f32x4 bb = b4p[f4i];
    const f32x4 v = x4[(size_t)tid];
    f32x4 o = (v - m) * r * w + bb;
    __builtin_nontemporal_store(o, &out4[(size_t)tid]);
}

extern "C" void kernel_launch(void* const* d_in, const int* in_sizes, int n_in,
                              void* d_out, int out_size, void* d_ws, size_t ws_size,
                              hipStream_t stream) {
    const f32x4* x = (const f32x4*)d_in[0];
    const f32x4* w = (const f32x4*)d_in[1];
    const f32x4* bias = (const f32x4*)d_in[2];
    const int* cp = (const int*)d_in[3];

    char* ws = (char*)d_ws;
    int*   meta  = (int*)ws;                 // [16]
    int*   ch_s0 = (int*)(ws + 2048);        // [CHCAP]
    int*   ch_s1 = (int*)(ws + 4096);        // [CHCAP]
    int*   ch_c0 = (int*)(ws + 6144);        // [CHCAP]
    int*   ch_n  = (int*)(ws + 8192);        // [CHCAP]
    int*   ch_seg= (int*)(ws + 10240);       // [CHCAP]
    float* ch_rc = (float*)(ws + 12288);     // [CHCAP]
    int*   ctr   = (int*)(ws + 32768);       // [CHCAP*BSZ] = 24 KB
    int*   seg_id= (int*)(ws + 65536);       // [SSZ]
    float* psum  = (float*)(ws + 131072);    // CHCAP*BSZ*FSZ = 6.29 MB
    float* pssq  = psum + (size_t)CHCAP * BSZ * F4 * 4;
    f32x4* mean4 = (f32x4*)(pssq + (size_t)CHCAP * BSZ * F4 * 4);  // 4.2 MB
    f32x4* rstd4 = mean4 + (size_t)SEGCAP * BSZ * F4;

    scan_kernel<<<1, 1024, 0, stream>>>(cp, ch_s0, ch_s1, ch_c0, ch_n, ch_seg,
                                        ch_rc, seg_id, ctr, meta);
    stats_kernel<<<NBLK_S, 256, 0, stream>>>(x, ch_s0, ch_s1, ch_c0, ch_n, ch_seg,
                                             ch_rc, meta, psum, pssq, ctr,
                                             mean4, rstd4);
    norm_kernel<<<BSZ * SSZ * F4 / 256, 256, 0, stream>>>(x, w, bias, seg_id,
                                                          mean4, rstd4,
                                                          (f32x4*)d_out);
}